// Round 1
// baseline (422.594 us; speedup 1.0000x reference)
//
#include <hip/hip_runtime.h>

#define N_NODES 50000
#define N_EDGES 600000
#define HID 128

// ---------------- CSR build ----------------

__global__ void k_deg(const int* __restrict__ dst, int* __restrict__ fill, int ne) {
    int e = blockIdx.x * blockDim.x + threadIdx.x;
    if (e < ne) atomicAdd(&fill[dst[e]], 1);
}

// single-block exclusive scan over degree counts; also writes inv_deg and resets fill
__global__ __launch_bounds__(256) void k_scan(int* __restrict__ fill, int* __restrict__ row_off,
                                              float* __restrict__ inv_deg, int n) {
    __shared__ int part[256];
    int tid = threadIdx.x;
    int seg = (n + 255) >> 8;
    int s0 = tid * seg;
    int s1 = min(s0 + seg, n);
    int sum = 0;
    for (int i = s0; i < s1; ++i) sum += fill[i];
    part[tid] = sum;
    __syncthreads();
    for (int off = 1; off < 256; off <<= 1) {
        int v = (tid >= off) ? part[tid - off] : 0;
        __syncthreads();
        part[tid] += v;
        __syncthreads();
    }
    int run = part[tid] - sum;  // exclusive prefix for this segment
    for (int i = s0; i < s1; ++i) {
        int c = fill[i];
        row_off[i] = run;
        inv_deg[i] = 1.0f / (float)max(c, 1);
        run += c;
        fill[i] = 0;  // reset for placement pass
    }
    if (tid == 255) row_off[n] = part[255];
}

__global__ void k_place(const int* __restrict__ src, const int* __restrict__ dst,
                        const int* __restrict__ row_off, int* __restrict__ fill,
                        int* __restrict__ csr, int ne) {
    int e = blockIdx.x * blockDim.x + threadIdx.x;
    if (e < ne) {
        int d = dst[e];
        int pos = atomicAdd(&fill[d], 1);
        csr[row_off[d] + pos] = src[e];
    }
}

// ---------------- weight prep: V[k][j] = k<128 ? Wl[j][k] : Wr[j][k-128] ----------------

__global__ void k_prepV(const float* __restrict__ W1l, const float* __restrict__ W1r,
                        const float* __restrict__ W2l, const float* __restrict__ W2r,
                        float* __restrict__ V1, float* __restrict__ V2) {
    int idx = blockIdx.x * blockDim.x + threadIdx.x;
    if (idx >= 2 * 256 * HID) return;
    int which = idx >= 256 * HID;
    int i = idx & (256 * HID - 1);
    int k = i >> 7, j = i & 127;
    float v;
    if (!which) v = (k < HID) ? W1l[j * HID + k] : W1r[j * HID + k - HID];
    else        v = (k < HID) ? W2l[j * HID + k] : W2r[j * HID + k - HID];
    if (!which) V1[i] = v; else V2[i] = v;
}

// ---------------- mean aggregation: one 32-lane group per node ----------------

__global__ __launch_bounds__(256) void k_agg(const float* __restrict__ x, const int* __restrict__ csr,
                                             const int* __restrict__ row_off,
                                             const float* __restrict__ inv_deg,
                                             float* __restrict__ agg, int n) {
    int g = (blockIdx.x * blockDim.x + threadIdx.x) >> 5;
    int lane = threadIdx.x & 31;
    if (g >= n) return;
    int e0 = row_off[g], e1 = row_off[g + 1];
    float ax = 0.f, ay = 0.f, az = 0.f, aw = 0.f;
    for (int e = e0; e < e1; ++e) {
        int s = csr[e];
        const float4 v = *(const float4*)(x + (size_t)s * HID + lane * 4);
        ax += v.x; ay += v.y; az += v.z; aw += v.w;
    }
    float inv = inv_deg[g];
    float4 o;
    o.x = ax * inv; o.y = ay * inv; o.z = az * inv; o.w = aw * inv;
    *(float4*)(agg + (size_t)g * HID + lane * 4) = o;
}

// ---------------- fused GEMM: out = [agg | xin] @ V + bias (optional relu) ----------------
// BM=64 rows/block, BN=128 (full width), BK=32, 256 threads, 8 rows x 4 cols per thread.

#define BM 64
#define BK 32

__global__ __launch_bounds__(256) void k_gemm(const float* __restrict__ agg,
                                              const float* __restrict__ xin,
                                              const float* __restrict__ V,
                                              const float* __restrict__ bias,
                                              float* __restrict__ out, int relu, int nrows) {
    __shared__ float AsT[BK][68];    // transposed A tile, padded (+4) to spread banks
    __shared__ float Bs[BK][HID];    // V tile

    int tid = threadIdx.x;
    int tx = tid & 31;       // col group: cols tx*4 .. tx*4+3
    int ty = tid >> 5;       // row group: rows ty*8 .. ty*8+7
    int r0 = blockIdx.x * BM;

    float4 acc[8];
#pragma unroll
    for (int i = 0; i < 8; ++i) acc[i] = make_float4(0.f, 0.f, 0.f, 0.f);

    for (int it = 0; it < 8; ++it) {
        int k0 = it * BK;
        const float* Asrc = (k0 < HID) ? agg : xin;
        int col = k0 & (HID - 1);

        // stage A: 64 rows x 32 cols = 512 float4 slots, transposed into AsT
#pragma unroll
        for (int q = 0; q < 2; ++q) {
            int s = tid + q * 256;
            int row = s >> 3, c4 = s & 7;
            int gr = r0 + row;
            float4 v = make_float4(0.f, 0.f, 0.f, 0.f);
            if (gr < nrows) v = *(const float4*)(Asrc + (size_t)gr * HID + col + c4 * 4);
            AsT[c4 * 4 + 0][row] = v.x;
            AsT[c4 * 4 + 1][row] = v.y;
            AsT[c4 * 4 + 2][row] = v.z;
            AsT[c4 * 4 + 3][row] = v.w;
        }
        // stage B: contiguous 32x128 block of V
        {
            const float4* Vt = (const float4*)(V + (size_t)k0 * HID);
            float4* BsV = (float4*)(&Bs[0][0]);
#pragma unroll
            for (int q = 0; q < 4; ++q) BsV[tid + q * 256] = Vt[tid + q * 256];
        }
        __syncthreads();

#pragma unroll
        for (int kk = 0; kk < BK; ++kk) {
            const float4 b  = *(const float4*)&Bs[kk][tx * 4];
            const float4 a0 = *(const float4*)&AsT[kk][ty * 8];
            const float4 a1 = *(const float4*)&AsT[kk][ty * 8 + 4];
            float a[8] = {a0.x, a0.y, a0.z, a0.w, a1.x, a1.y, a1.z, a1.w};
#pragma unroll
            for (int i = 0; i < 8; ++i) {
                acc[i].x = fmaf(a[i], b.x, acc[i].x);
                acc[i].y = fmaf(a[i], b.y, acc[i].y);
                acc[i].z = fmaf(a[i], b.z, acc[i].z);
                acc[i].w = fmaf(a[i], b.w, acc[i].w);
            }
        }
        __syncthreads();
    }

    float4 bv = *(const float4*)(bias + tx * 4);
#pragma unroll
    for (int i = 0; i < 8; ++i) {
        int gr = r0 + ty * 8 + i;
        if (gr < nrows) {
            float4 o;
            o.x = acc[i].x + bv.x;
            o.y = acc[i].y + bv.y;
            o.z = acc[i].z + bv.z;
            o.w = acc[i].w + bv.w;
            if (relu) {
                o.x = fmaxf(o.x, 0.f);
                o.y = fmaxf(o.y, 0.f);
                o.z = fmaxf(o.z, 0.f);
                o.w = fmaxf(o.w, 0.f);
            }
            *(float4*)(out + (size_t)gr * HID + tx * 4) = o;
        }
    }
}

// ---------------- launch ----------------

extern "C" void kernel_launch(void* const* d_in, const int* in_sizes, int n_in,
                              void* d_out, int out_size, void* d_ws, size_t ws_size,
                              hipStream_t stream) {
    const float* x   = (const float*)d_in[0];
    const int*   ei  = (const int*)d_in[1];
    const float* W1l = (const float*)d_in[2];
    const float* b1l = (const float*)d_in[3];
    const float* W1r = (const float*)d_in[4];
    const float* W2l = (const float*)d_in[5];
    const float* b2l = (const float*)d_in[6];
    const float* W2r = (const float*)d_in[7];
    float* out = (float*)d_out;

    const int* src = ei;            // edge_index[0]
    const int* dst = ei + N_EDGES;  // edge_index[1]

    char* w = (char*)d_ws;
    // 256-aligned workspace layout
    float* agg     = (float*)(w);                                   // 25,600,000 B
    int*   row_off = (int*)(w + 25600000);                          //   200,192 B (50001 ints, padded)
    int*   fill    = (int*)(w + 25600000 + 200192);                 //   200,192 B
    int*   csr     = (int*)(w + 25600000 + 2 * 200192);             // 2,400,000 B
    float* inv_deg = (float*)(w + 25600000 + 2 * 200192 + 2400000); //   200,192 B
    float* V1      = (float*)(w + 25600000 + 3 * 200192 + 2400000);           // 131,072 B
    float* V2      = (float*)(w + 25600000 + 3 * 200192 + 2400000 + 131072);  // 131,072 B

    // 1) zero degree counters
    hipMemsetAsync(fill, 0, N_NODES * sizeof(int), stream);

    // 2) degree histogram
    k_deg<<<(N_EDGES + 255) / 256, 256, 0, stream>>>(dst, fill, N_EDGES);

    // 3) exclusive scan -> row_off, inv_deg; resets fill
    k_scan<<<1, 256, 0, stream>>>(fill, row_off, inv_deg, N_NODES);

    // 4) place edges into CSR buckets
    k_place<<<(N_EDGES + 255) / 256, 256, 0, stream>>>(src, dst, row_off, fill, csr, N_EDGES);

    // 5) materialize fused weight matrices V1, V2 ([256][128], row-major)
    k_prepV<<<(2 * 256 * HID + 255) / 256, 256, 0, stream>>>(W1l, W1r, W2l, W2r, V1, V2);

    // ---- layer 1 ----
    k_agg<<<(N_NODES * 32 + 255) / 256, 256, 0, stream>>>(x, csr, row_off, inv_deg, agg, N_NODES);
    k_gemm<<<(N_NODES + BM - 1) / BM, 256, 0, stream>>>(agg, x, V1, b1l, out, 1, N_NODES);

    // ---- layer 2 (h lives in d_out; GEMM writes in place, each block reads its own rows first) ----
    k_agg<<<(N_NODES * 32 + 255) / 256, 256, 0, stream>>>(out, csr, row_off, inv_deg, agg, N_NODES);
    k_gemm<<<(N_NODES + BM - 1) / BM, 256, 0, stream>>>(agg, out, V2, b2l, out, 0, N_NODES);
}

// Round 2
// 284.504 us; speedup vs baseline: 1.4854x; 1.4854x over previous
//
#include <hip/hip_runtime.h>

#define N_NODES 50000
#define N_EDGES 600000
#define HID 128
#define SCAN_BLOCKS ((N_NODES + 255) / 256)   // 196

// ---------------- CSR build ----------------

__global__ void k_deg(const int* __restrict__ dst, int* __restrict__ fill, int ne) {
    int e = blockIdx.x * blockDim.x + threadIdx.x;
    if (e < ne) atomicAdd(&fill[dst[e]], 1);
}

// stage 1: per-block sums of fill[]
__global__ __launch_bounds__(256) void k_bsum(const int* __restrict__ fill, int* __restrict__ bsum, int n) {
    __shared__ int s[256];
    int tid = threadIdx.x;
    int i = blockIdx.x * 256 + tid;
    s[tid] = (i < n) ? fill[i] : 0;
    __syncthreads();
#pragma unroll
    for (int off = 128; off > 0; off >>= 1) {
        if (tid < off) s[tid] += s[tid + off];
        __syncthreads();
    }
    if (tid == 0) bsum[blockIdx.x] = s[0];
}

// stage 2: single-block exclusive scan of the block sums (nb <= 256)
__global__ __launch_bounds__(256) void k_scan_bsum(int* __restrict__ bsum, int* __restrict__ row_off,
                                                   int nb, int n) {
    __shared__ int s[256];
    int tid = threadIdx.x;
    int v = (tid < nb) ? bsum[tid] : 0;
    s[tid] = v;
    __syncthreads();
#pragma unroll
    for (int off = 1; off < 256; off <<= 1) {
        int t = (tid >= off) ? s[tid - off] : 0;
        __syncthreads();
        s[tid] += t;
        __syncthreads();
    }
    if (tid < nb) bsum[tid] = s[tid] - v;   // exclusive prefix of block sums
    if (tid == 255) row_off[n] = s[255];    // grand total
}

// stage 3: intra-block exclusive scan + block offset -> row_off; inv_deg; reset fill
__global__ __launch_bounds__(256) void k_write_off(int* __restrict__ fill, const int* __restrict__ bsum,
                                                   int* __restrict__ row_off, float* __restrict__ inv_deg,
                                                   int n) {
    __shared__ int s[256];
    int tid = threadIdx.x;
    int i = blockIdx.x * 256 + tid;
    int c = (i < n) ? fill[i] : 0;
    s[tid] = c;
    __syncthreads();
#pragma unroll
    for (int off = 1; off < 256; off <<= 1) {
        int t = (tid >= off) ? s[tid - off] : 0;
        __syncthreads();
        s[tid] += t;
        __syncthreads();
    }
    if (i < n) {
        row_off[i] = bsum[blockIdx.x] + s[tid] - c;
        inv_deg[i] = 1.0f / (float)max(c, 1);
        fill[i] = 0;  // reset for placement pass
    }
}

__global__ void k_place(const int* __restrict__ src, const int* __restrict__ dst,
                        const int* __restrict__ row_off, int* __restrict__ fill,
                        int* __restrict__ csr, int ne) {
    int e = blockIdx.x * blockDim.x + threadIdx.x;
    if (e < ne) {
        int d = dst[e];
        int pos = atomicAdd(&fill[d], 1);
        csr[row_off[d] + pos] = src[e];
    }
}

// ---------------- weight prep: V[k][j] = k<128 ? Wl[j][k] : Wr[j][k-128] ----------------

__global__ void k_prepV(const float* __restrict__ W1l, const float* __restrict__ W1r,
                        const float* __restrict__ W2l, const float* __restrict__ W2r,
                        float* __restrict__ V1, float* __restrict__ V2) {
    int idx = blockIdx.x * blockDim.x + threadIdx.x;
    if (idx >= 2 * 256 * HID) return;
    int which = idx >= 256 * HID;
    int i = idx & (256 * HID - 1);
    int k = i >> 7, j = i & 127;
    float v;
    if (!which) v = (k < HID) ? W1l[j * HID + k] : W1r[j * HID + k - HID];
    else        v = (k < HID) ? W2l[j * HID + k] : W2r[j * HID + k - HID];
    if (!which) V1[i] = v; else V2[i] = v;
}

// ---------------- mean aggregation: one 32-lane group per node ----------------

__global__ __launch_bounds__(256) void k_agg(const float* __restrict__ x, const int* __restrict__ csr,
                                             const int* __restrict__ row_off,
                                             const float* __restrict__ inv_deg,
                                             float* __restrict__ agg, int n) {
    int g = (blockIdx.x * blockDim.x + threadIdx.x) >> 5;
    int lane = threadIdx.x & 31;
    if (g >= n) return;
    int e0 = row_off[g], e1 = row_off[g + 1];
    float ax = 0.f, ay = 0.f, az = 0.f, aw = 0.f;
    for (int e = e0; e < e1; ++e) {
        int s = csr[e];
        const float4 v = *(const float4*)(x + (size_t)s * HID + lane * 4);
        ax += v.x; ay += v.y; az += v.z; aw += v.w;
    }
    float inv = inv_deg[g];
    float4 o;
    o.x = ax * inv; o.y = ay * inv; o.z = az * inv; o.w = aw * inv;
    *(float4*)(agg + (size_t)g * HID + lane * 4) = o;
}

// ---------------- fused GEMM: out = [agg | xin] @ V + bias (optional relu) ----------------
// BM=64 rows/block, BN=128 (full width), BK=32, 256 threads, 8 rows x 4 cols per thread.

#define BM 64
#define BK 32

__global__ __launch_bounds__(256) void k_gemm(const float* __restrict__ agg,
                                              const float* __restrict__ xin,
                                              const float* __restrict__ V,
                                              const float* __restrict__ bias,
                                              float* __restrict__ out, int relu, int nrows) {
    __shared__ float AsT[BK][68];    // transposed A tile, padded (+4) to spread banks
    __shared__ float Bs[BK][HID];    // V tile

    int tid = threadIdx.x;
    int tx = tid & 31;       // col group: cols tx*4 .. tx*4+3
    int ty = tid >> 5;       // row group: rows ty*8 .. ty*8+7
    int r0 = blockIdx.x * BM;

    float4 acc[8];
#pragma unroll
    for (int i = 0; i < 8; ++i) acc[i] = make_float4(0.f, 0.f, 0.f, 0.f);

    for (int it = 0; it < 8; ++it) {
        int k0 = it * BK;
        const float* Asrc = (k0 < HID) ? agg : xin;
        int col = k0 & (HID - 1);

        // stage A: 64 rows x 32 cols = 512 float4 slots, transposed into AsT
#pragma unroll
        for (int q = 0; q < 2; ++q) {
            int s = tid + q * 256;
            int row = s >> 3, c4 = s & 7;
            int gr = r0 + row;
            float4 v = make_float4(0.f, 0.f, 0.f, 0.f);
            if (gr < nrows) v = *(const float4*)(Asrc + (size_t)gr * HID + col + c4 * 4);
            AsT[c4 * 4 + 0][row] = v.x;
            AsT[c4 * 4 + 1][row] = v.y;
            AsT[c4 * 4 + 2][row] = v.z;
            AsT[c4 * 4 + 3][row] = v.w;
        }
        // stage B: contiguous 32x128 block of V
        {
            const float4* Vt = (const float4*)(V + (size_t)k0 * HID);
            float4* BsV = (float4*)(&Bs[0][0]);
#pragma unroll
            for (int q = 0; q < 4; ++q) BsV[tid + q * 256] = Vt[tid + q * 256];
        }
        __syncthreads();

#pragma unroll
        for (int kk = 0; kk < BK; ++kk) {
            const float4 b  = *(const float4*)&Bs[kk][tx * 4];
            const float4 a0 = *(const float4*)&AsT[kk][ty * 8];
            const float4 a1 = *(const float4*)&AsT[kk][ty * 8 + 4];
            float a[8] = {a0.x, a0.y, a0.z, a0.w, a1.x, a1.y, a1.z, a1.w};
#pragma unroll
            for (int i = 0; i < 8; ++i) {
                acc[i].x = fmaf(a[i], b.x, acc[i].x);
                acc[i].y = fmaf(a[i], b.y, acc[i].y);
                acc[i].z = fmaf(a[i], b.z, acc[i].z);
                acc[i].w = fmaf(a[i], b.w, acc[i].w);
            }
        }
        __syncthreads();
    }

    float4 bv = *(const float4*)(bias + tx * 4);
#pragma unroll
    for (int i = 0; i < 8; ++i) {
        int gr = r0 + ty * 8 + i;
        if (gr < nrows) {
            float4 o;
            o.x = acc[i].x + bv.x;
            o.y = acc[i].y + bv.y;
            o.z = acc[i].z + bv.z;
            o.w = acc[i].w + bv.w;
            if (relu) {
                o.x = fmaxf(o.x, 0.f);
                o.y = fmaxf(o.y, 0.f);
                o.z = fmaxf(o.z, 0.f);
                o.w = fmaxf(o.w, 0.f);
            }
            *(float4*)(out + (size_t)gr * HID + tx * 4) = o;
        }
    }
}

// ---------------- launch ----------------

extern "C" void kernel_launch(void* const* d_in, const int* in_sizes, int n_in,
                              void* d_out, int out_size, void* d_ws, size_t ws_size,
                              hipStream_t stream) {
    const float* x   = (const float*)d_in[0];
    const int*   ei  = (const int*)d_in[1];
    const float* W1l = (const float*)d_in[2];
    const float* b1l = (const float*)d_in[3];
    const float* W1r = (const float*)d_in[4];
    const float* W2l = (const float*)d_in[5];
    const float* b2l = (const float*)d_in[6];
    const float* W2r = (const float*)d_in[7];
    float* out = (float*)d_out;

    const int* src = ei;            // edge_index[0]
    const int* dst = ei + N_EDGES;  // edge_index[1]

    char* w = (char*)d_ws;
    // 256-aligned workspace layout
    float* agg     = (float*)(w);                                   // 25,600,000 B
    int*   row_off = (int*)(w + 25600000);                          //   200,192 B (50001 ints, padded)
    int*   fill    = (int*)(w + 25600000 + 200192);                 //   200,192 B
    int*   csr     = (int*)(w + 25600000 + 2 * 200192);             // 2,400,000 B
    float* inv_deg = (float*)(w + 25600000 + 2 * 200192 + 2400000); //   200,192 B
    float* V1      = (float*)(w + 25600000 + 3 * 200192 + 2400000);           // 131,072 B
    float* V2      = (float*)(w + 25600000 + 3 * 200192 + 2400000 + 131072);  // 131,072 B
    int*   bsum    = (int*)(w + 25600000 + 3 * 200192 + 2400000 + 2 * 131072); // 1,024 B

    // 1) zero degree counters
    hipMemsetAsync(fill, 0, N_NODES * sizeof(int), stream);

    // 2) degree histogram
    k_deg<<<(N_EDGES + 255) / 256, 256, 0, stream>>>(dst, fill, N_EDGES);

    // 3) hierarchical exclusive scan -> row_off, inv_deg; resets fill
    k_bsum<<<SCAN_BLOCKS, 256, 0, stream>>>(fill, bsum, N_NODES);
    k_scan_bsum<<<1, 256, 0, stream>>>(bsum, row_off, SCAN_BLOCKS, N_NODES);
    k_write_off<<<SCAN_BLOCKS, 256, 0, stream>>>(fill, bsum, row_off, inv_deg, N_NODES);

    // 4) place edges into CSR buckets
    k_place<<<(N_EDGES + 255) / 256, 256, 0, stream>>>(src, dst, row_off, fill, csr, N_EDGES);

    // 5) materialize fused weight matrices V1, V2 ([256][128], row-major)
    k_prepV<<<(2 * 256 * HID + 255) / 256, 256, 0, stream>>>(W1l, W1r, W2l, W2r, V1, V2);

    // ---- layer 1 ----
    k_agg<<<(N_NODES * 32 + 255) / 256, 256, 0, stream>>>(x, csr, row_off, inv_deg, agg, N_NODES);
    k_gemm<<<(N_NODES + BM - 1) / BM, 256, 0, stream>>>(agg, x, V1, b1l, out, 1, N_NODES);

    // ---- layer 2 (h lives in d_out; GEMM writes in place, each block reads its own rows first) ----
    k_agg<<<(N_NODES * 32 + 255) / 256, 256, 0, stream>>>(out, csr, row_off, inv_deg, agg, N_NODES);
    k_gemm<<<(N_NODES + BM - 1) / BM, 256, 0, stream>>>(agg, out, V2, b2l, out, 0, N_NODES);
}

// Round 3
// 205.912 us; speedup vs baseline: 2.0523x; 1.3817x over previous
//
#include <hip/hip_runtime.h>
#include <hip/hip_bf16.h>

#define N_NODES 50000
#define N_EDGES 600000
#define HID 128
#define SCAN_BLOCKS ((N_NODES + 255) / 256)   // 196

typedef __attribute__((ext_vector_type(8))) __bf16 bf16x8;
typedef __attribute__((ext_vector_type(4))) float f32x4;

static __device__ __forceinline__ unsigned short f2b(float v) {
    return __builtin_bit_cast(unsigned short, (__bf16)v);
}

// ---------------- CSR build ----------------

__global__ void k_deg(const int* __restrict__ dst, int* __restrict__ fill, int ne) {
    int e = blockIdx.x * blockDim.x + threadIdx.x;
    if (e < ne) atomicAdd(&fill[dst[e]], 1);
}

__global__ __launch_bounds__(256) void k_bsum(const int* __restrict__ fill, int* __restrict__ bsum, int n) {
    __shared__ int s[256];
    int tid = threadIdx.x;
    int i = blockIdx.x * 256 + tid;
    s[tid] = (i < n) ? fill[i] : 0;
    __syncthreads();
#pragma unroll
    for (int off = 128; off > 0; off >>= 1) {
        if (tid < off) s[tid] += s[tid + off];
        __syncthreads();
    }
    if (tid == 0) bsum[blockIdx.x] = s[0];
}

__global__ __launch_bounds__(256) void k_scan_bsum(int* __restrict__ bsum, int* __restrict__ row_off,
                                                   int nb, int n) {
    __shared__ int s[256];
    int tid = threadIdx.x;
    int v = (tid < nb) ? bsum[tid] : 0;
    s[tid] = v;
    __syncthreads();
#pragma unroll
    for (int off = 1; off < 256; off <<= 1) {
        int t = (tid >= off) ? s[tid - off] : 0;
        __syncthreads();
        s[tid] += t;
        __syncthreads();
    }
    if (tid < nb) bsum[tid] = s[tid] - v;
    if (tid == 255) row_off[n] = s[255];
}

__global__ __launch_bounds__(256) void k_write_off(int* __restrict__ fill, const int* __restrict__ bsum,
                                                   int* __restrict__ row_off, float* __restrict__ inv_deg,
                                                   int n) {
    __shared__ int s[256];
    int tid = threadIdx.x;
    int i = blockIdx.x * 256 + tid;
    int c = (i < n) ? fill[i] : 0;
    s[tid] = c;
    __syncthreads();
#pragma unroll
    for (int off = 1; off < 256; off <<= 1) {
        int t = (tid >= off) ? s[tid - off] : 0;
        __syncthreads();
        s[tid] += t;
        __syncthreads();
    }
    if (i < n) {
        row_off[i] = bsum[blockIdx.x] + s[tid] - c;
        inv_deg[i] = 1.0f / (float)max(c, 1);
        fill[i] = 0;
    }
}

__global__ void k_place(const int* __restrict__ src, const int* __restrict__ dst,
                        const int* __restrict__ row_off, int* __restrict__ fill,
                        int* __restrict__ csr, int ne) {
    int e = blockIdx.x * blockDim.x + threadIdx.x;
    if (e < ne) {
        int d = dst[e];
        int pos = atomicAdd(&fill[d], 1);
        csr[row_off[d] + pos] = src[e];
    }
}

// ---------------- x -> bf16 cast ----------------

__global__ void k_cast(const float* __restrict__ x, unsigned short* __restrict__ xb, int n4) {
    int i = blockIdx.x * blockDim.x + threadIdx.x;
    if (i >= n4) return;
    float4 v = *(const float4*)(x + (size_t)i * 4);
    ushort4 o;
    o.x = f2b(v.x); o.y = f2b(v.y); o.z = f2b(v.z); o.w = f2b(v.w);
    *(ushort4*)(xb + (size_t)i * 4) = o;
}

// ---------------- weight prep: V_T[j][k] bf16, k<128 -> Wl[j][k], else Wr[j][k-128] ----------------

__global__ void k_prepV(const float* __restrict__ W1l, const float* __restrict__ W1r,
                        const float* __restrict__ W2l, const float* __restrict__ W2r,
                        unsigned short* __restrict__ V1, unsigned short* __restrict__ V2) {
    int idx = blockIdx.x * blockDim.x + threadIdx.x;
    if (idx >= 2 * 128 * 256) return;
    int which = idx >> 15;
    int i = idx & 32767;
    int j = i >> 8, k = i & 255;
    const float* Wl = which ? W2l : W1l;
    const float* Wr = which ? W2r : W1r;
    float v = (k < HID) ? Wl[j * HID + k] : Wr[j * HID + k - HID];
    (which ? V2 : V1)[i] = f2b(v);
}

// ---------------- mean aggregation (bf16 in, bf16 out, fp32 accum) ----------------

__global__ __launch_bounds__(256) void k_agg(const unsigned short* __restrict__ xb,
                                             const int* __restrict__ csr,
                                             const int* __restrict__ row_off,
                                             const float* __restrict__ inv_deg,
                                             unsigned short* __restrict__ aggB, int n) {
    int g = (blockIdx.x * blockDim.x + threadIdx.x) >> 5;
    int lane = threadIdx.x & 31;
    if (g >= n) return;
    int e0 = row_off[g], e1 = row_off[g + 1];
    float a0 = 0.f, a1 = 0.f, a2 = 0.f, a3 = 0.f;
    for (int e = e0; e < e1; ++e) {
        int s = csr[e];
        uint2 v = *(const uint2*)(xb + (size_t)s * HID + lane * 4);
        a0 += __uint_as_float(v.x << 16);
        a1 += __uint_as_float(v.x & 0xffff0000u);
        a2 += __uint_as_float(v.y << 16);
        a3 += __uint_as_float(v.y & 0xffff0000u);
    }
    float inv = inv_deg[g];
    ushort4 o;
    o.x = f2b(a0 * inv); o.y = f2b(a1 * inv); o.z = f2b(a2 * inv); o.w = f2b(a3 * inv);
    *(ushort4*)(aggB + (size_t)g * HID + lane * 4) = o;
}

// ---------------- MFMA GEMM: out = [agg | xin] @ V_T^T + bias ----------------
// 512 threads (8 waves), BM=128 rows/block, full N=128, K=256 in 2 phases of 128.
// LDS: A 128x128 bf16 (32KB) + B 128x128 bf16 (32KB), XOR-swizzled rows.

__global__ __launch_bounds__(512) void k_gemm(const unsigned short* __restrict__ aggB,
                                              const unsigned short* __restrict__ xinB,
                                              const unsigned short* __restrict__ VT,
                                              const float* __restrict__ bias,
                                              float* __restrict__ outF,
                                              unsigned short* __restrict__ outB,
                                              int mode /*1 = relu+bf16 out, 0 = fp32 out*/,
                                              int nrows) {
    __shared__ char As[32768];
    __shared__ char Bs[32768];
    int tid = threadIdx.x;
    int w = tid >> 6, l = tid & 63;
    int r0 = blockIdx.x * 128;

    f32x4 acc[8] = {};

    int arow = w * 16 + (l & 15);
    int kgrp = (l >> 4) * 8;

    for (int p = 0; p < 2; ++p) {
        const unsigned short* Asrc = p ? xinB : aggB;
        // stage A: 128 rows x 128 k = 2048 x 16B chunks
#pragma unroll
        for (int q = 0; q < 4; ++q) {
            int c = tid + q * 512;
            int m = c >> 4, c16 = c & 15;
            int gr = r0 + m;
            uint4 v = make_uint4(0, 0, 0, 0);
            if (gr < nrows) v = *(const uint4*)(Asrc + (size_t)gr * HID + c16 * 8);
            int byt = (m * 256 + c16 * 16) ^ ((m & 7) << 4);
            *(uint4*)(As + byt) = v;
        }
        // stage B: V_T rows j, k-half p
#pragma unroll
        for (int q = 0; q < 4; ++q) {
            int c = tid + q * 512;
            int j = c >> 4, c16 = c & 15;
            uint4 v = *(const uint4*)(VT + (size_t)j * 256 + p * 128 + c16 * 8);
            int byt = (j * 256 + c16 * 16) ^ ((j & 7) << 4);
            *(uint4*)(Bs + byt) = v;
        }
        __syncthreads();

#pragma unroll
        for (int s = 0; s < 4; ++s) {
            int koff = (s * 32 + kgrp) * 2;
            bf16x8 a = *(const bf16x8*)(As + ((arow * 256 + koff) ^ ((arow & 7) << 4)));
#pragma unroll
            for (int cc = 0; cc < 8; ++cc) {
                int brow = cc * 16 + (l & 15);
                bf16x8 b = *(const bf16x8*)(Bs + ((brow * 256 + koff) ^ ((brow & 7) << 4)));
                acc[cc] = __builtin_amdgcn_mfma_f32_16x16x32_bf16(a, b, acc[cc], 0, 0, 0);
            }
        }
        __syncthreads();
    }

    // epilogue: D[row=(l>>4)*4+i][col=cc*16+(l&15)] per wave tile
    int lo = l & 15, hi = l >> 4;
#pragma unroll
    for (int cc = 0; cc < 8; ++cc) {
        int col = cc * 16 + lo;
        float bv = bias[col];
#pragma unroll
        for (int i = 0; i < 4; ++i) {
            int gr = r0 + w * 16 + hi * 4 + i;
            if (gr < nrows) {
                float v = acc[cc][i] + bv;
                if (mode) {
                    v = fmaxf(v, 0.f);
                    outB[(size_t)gr * HID + col] = f2b(v);
                } else {
                    outF[(size_t)gr * HID + col] = v;
                }
            }
        }
    }
}

// ---------------- launch ----------------

extern "C" void kernel_launch(void* const* d_in, const int* in_sizes, int n_in,
                              void* d_out, int out_size, void* d_ws, size_t ws_size,
                              hipStream_t stream) {
    const float* x   = (const float*)d_in[0];
    const int*   ei  = (const int*)d_in[1];
    const float* W1l = (const float*)d_in[2];
    const float* b1l = (const float*)d_in[3];
    const float* W1r = (const float*)d_in[4];
    const float* W2l = (const float*)d_in[5];
    const float* b2l = (const float*)d_in[6];
    const float* W2r = (const float*)d_in[7];
    float* out = (float*)d_out;

    const int* src = ei;
    const int* dst = ei + N_EDGES;

    char* w = (char*)d_ws;
    unsigned short* aggB = (unsigned short*)(w);                    // 12,800,000 B
    unsigned short* buf0 = (unsigned short*)(w + 12800000);         // 12,800,000 B (xb, then hb in place)
    int*   csr     = (int*)(w + 25600000);                          //  2,400,000 B
    int*   row_off = (int*)(w + 28000000);                          //    200,192 B
    int*   fill    = (int*)(w + 28200192);                          //    200,192 B
    float* inv_deg = (float*)(w + 28400384);                        //    200,192 B
    unsigned short* V1 = (unsigned short*)(w + 28600576);           //     65,536 B
    unsigned short* V2 = (unsigned short*)(w + 28666112);           //     65,536 B
    int*   bsum    = (int*)(w + 28731648);                          //      1,024 B

    // CSR build
    hipMemsetAsync(fill, 0, N_NODES * sizeof(int), stream);
    k_deg<<<(N_EDGES + 255) / 256, 256, 0, stream>>>(dst, fill, N_EDGES);
    k_bsum<<<SCAN_BLOCKS, 256, 0, stream>>>(fill, bsum, N_NODES);
    k_scan_bsum<<<1, 256, 0, stream>>>(bsum, row_off, SCAN_BLOCKS, N_NODES);
    k_write_off<<<SCAN_BLOCKS, 256, 0, stream>>>(fill, bsum, row_off, inv_deg, N_NODES);
    k_place<<<(N_EDGES + 255) / 256, 256, 0, stream>>>(src, dst, row_off, fill, csr, N_EDGES);

    // weights + x cast
    k_prepV<<<(2 * 128 * 256 + 255) / 256, 256, 0, stream>>>(W1l, W1r, W2l, W2r, V1, V2);
    k_cast<<<(N_NODES * HID / 4 + 255) / 256, 256, 0, stream>>>(x, buf0, N_NODES * HID / 4);

    const int gemm_grid = (N_NODES + 127) / 128;  // 391

    // layer 1: agg1 <- mean(xb); h(bf16, relu) -> buf0 in place
    k_agg<<<(N_NODES * 32 + 255) / 256, 256, 0, stream>>>(buf0, csr, row_off, inv_deg, aggB, N_NODES);
    k_gemm<<<gemm_grid, 512, 0, stream>>>(aggB, buf0, V1, b1l, out, buf0, 1, N_NODES);

    // layer 2: agg2 <- mean(hb); out(fp32) -> d_out
    k_agg<<<(N_NODES * 32 + 255) / 256, 256, 0, stream>>>(buf0, csr, row_off, inv_deg, aggB, N_NODES);
    k_gemm<<<gemm_grid, 512, 0, stream>>>(aggB, buf0, V2, b2l, out, buf0, 0, N_NODES);
}

// Round 4
// 165.936 us; speedup vs baseline: 2.5467x; 1.2409x over previous
//
#include <hip/hip_runtime.h>
#include <hip/hip_bf16.h>

#define N_NODES 50000
#define N_EDGES 600000
#define HID 128
#define SCAN_BLOCKS ((N_NODES + 255) / 256)   // 196

typedef __attribute__((ext_vector_type(8))) __bf16 bf16x8;
typedef __attribute__((ext_vector_type(4))) float f32x4;

static __device__ __forceinline__ unsigned short f2b(float v) {
    return __builtin_bit_cast(unsigned short, (__bf16)v);
}

// ---------------- CSR build ----------------

__global__ void k_deg(const int* __restrict__ dst, int* __restrict__ fill, int ne) {
    int e = blockIdx.x * blockDim.x + threadIdx.x;
    if (e < ne) atomicAdd(&fill[dst[e]], 1);
}

__global__ __launch_bounds__(256) void k_bsum(const int* __restrict__ fill, int* __restrict__ bsum, int n) {
    __shared__ int s[256];
    int tid = threadIdx.x;
    int i = blockIdx.x * 256 + tid;
    s[tid] = (i < n) ? fill[i] : 0;
    __syncthreads();
#pragma unroll
    for (int off = 128; off > 0; off >>= 1) {
        if (tid < off) s[tid] += s[tid + off];
        __syncthreads();
    }
    if (tid == 0) bsum[blockIdx.x] = s[0];
}

__global__ __launch_bounds__(256) void k_scan_bsum(int* __restrict__ bsum, int* __restrict__ row_off,
                                                   int nb, int n) {
    __shared__ int s[256];
    int tid = threadIdx.x;
    int v = (tid < nb) ? bsum[tid] : 0;
    s[tid] = v;
    __syncthreads();
#pragma unroll
    for (int off = 1; off < 256; off <<= 1) {
        int t = (tid >= off) ? s[tid - off] : 0;
        __syncthreads();
        s[tid] += t;
        __syncthreads();
    }
    if (tid < nb) bsum[tid] = s[tid] - v;
    if (tid == 255) row_off[n] = s[255];
}

__global__ __launch_bounds__(256) void k_write_off(int* __restrict__ fill, const int* __restrict__ bsum,
                                                   int* __restrict__ row_off, float* __restrict__ inv_deg,
                                                   int n) {
    __shared__ int s[256];
    int tid = threadIdx.x;
    int i = blockIdx.x * 256 + tid;
    int c = (i < n) ? fill[i] : 0;
    s[tid] = c;
    __syncthreads();
#pragma unroll
    for (int off = 1; off < 256; off <<= 1) {
        int t = (tid >= off) ? s[tid - off] : 0;
        __syncthreads();
        s[tid] += t;
        __syncthreads();
    }
    if (i < n) {
        row_off[i] = bsum[blockIdx.x] + s[tid] - c;
        inv_deg[i] = 1.0f / (float)max(c, 1);
        fill[i] = 0;
    }
}

__global__ void k_place(const int* __restrict__ src, const int* __restrict__ dst,
                        const int* __restrict__ row_off, int* __restrict__ fill,
                        int* __restrict__ csr, int ne) {
    int e = blockIdx.x * blockDim.x + threadIdx.x;
    if (e < ne) {
        int d = dst[e];
        int pos = atomicAdd(&fill[d], 1);
        csr[row_off[d] + pos] = src[e];
    }
}

// ---------------- x -> bf16 cast ----------------

__global__ void k_cast(const float* __restrict__ x, unsigned short* __restrict__ xb, int n4) {
    int i = blockIdx.x * blockDim.x + threadIdx.x;
    if (i >= n4) return;
    float4 v = *(const float4*)(x + (size_t)i * 4);
    ushort4 o;
    o.x = f2b(v.x); o.y = f2b(v.y); o.z = f2b(v.z); o.w = f2b(v.w);
    *(ushort4*)(xb + (size_t)i * 4) = o;
}

// ---------------- weight prep: V_T[j][k] bf16, k<128 -> Wl[j][k], else Wr[j][k-128] ----------------

__global__ void k_prepV(const float* __restrict__ W1l, const float* __restrict__ W1r,
                        const float* __restrict__ W2l, const float* __restrict__ W2r,
                        unsigned short* __restrict__ V1, unsigned short* __restrict__ V2) {
    int idx = blockIdx.x * blockDim.x + threadIdx.x;
    if (idx >= 2 * 128 * 256) return;
    int which = idx >> 15;
    int i = idx & 32767;
    int j = i >> 8, k = i & 255;
    const float* Wl = which ? W2l : W1l;
    const float* Wr = which ? W2r : W1r;
    float v = (k < HID) ? Wl[j * HID + k] : Wr[j * HID + k - HID];
    (which ? V2 : V1)[i] = f2b(v);
}

// ---------------- mean aggregation (bf16 in/out, fp32 accum), 4-way MLP unroll ----------------

static __device__ __forceinline__ void acc_bf2(uint2 v, float& a0, float& a1, float& a2, float& a3) {
    a0 += __uint_as_float(v.x << 16);
    a1 += __uint_as_float(v.x & 0xffff0000u);
    a2 += __uint_as_float(v.y << 16);
    a3 += __uint_as_float(v.y & 0xffff0000u);
}

__global__ __launch_bounds__(256) void k_agg(const unsigned short* __restrict__ xb,
                                             const int* __restrict__ csr,
                                             const int* __restrict__ row_off,
                                             const float* __restrict__ inv_deg,
                                             unsigned short* __restrict__ aggB, int n) {
    int g = (blockIdx.x * blockDim.x + threadIdx.x) >> 5;
    int lane = threadIdx.x & 31;
    if (g >= n) return;
    int e0 = row_off[g], e1 = row_off[g + 1];
    float a0 = 0.f, a1 = 0.f, a2 = 0.f, a3 = 0.f;
    int e = e0;
    // 4-way unrolled body: 4 independent gathers in flight
    for (; e + 4 <= e1; e += 4) {
        int s0 = csr[e + 0];
        int s1 = csr[e + 1];
        int s2 = csr[e + 2];
        int s3 = csr[e + 3];
        uint2 v0 = *(const uint2*)(xb + (size_t)s0 * HID + lane * 4);
        uint2 v1 = *(const uint2*)(xb + (size_t)s1 * HID + lane * 4);
        uint2 v2 = *(const uint2*)(xb + (size_t)s2 * HID + lane * 4);
        uint2 v3 = *(const uint2*)(xb + (size_t)s3 * HID + lane * 4);
        acc_bf2(v0, a0, a1, a2, a3);
        acc_bf2(v1, a0, a1, a2, a3);
        acc_bf2(v2, a0, a1, a2, a3);
        acc_bf2(v3, a0, a1, a2, a3);
    }
    // tail (<=3 edges), still overlapped
    if (e + 2 <= e1) {
        int s0 = csr[e + 0];
        int s1 = csr[e + 1];
        uint2 v0 = *(const uint2*)(xb + (size_t)s0 * HID + lane * 4);
        uint2 v1 = *(const uint2*)(xb + (size_t)s1 * HID + lane * 4);
        acc_bf2(v0, a0, a1, a2, a3);
        acc_bf2(v1, a0, a1, a2, a3);
        e += 2;
    }
    if (e < e1) {
        int s0 = csr[e];
        uint2 v0 = *(const uint2*)(xb + (size_t)s0 * HID + lane * 4);
        acc_bf2(v0, a0, a1, a2, a3);
    }
    float inv = inv_deg[g];
    ushort4 o;
    o.x = f2b(a0 * inv); o.y = f2b(a1 * inv); o.z = f2b(a2 * inv); o.w = f2b(a3 * inv);
    *(ushort4*)(aggB + (size_t)g * HID + lane * 4) = o;
}

// ---------------- MFMA GEMM: out = [agg | xin] @ V_T^T + bias ----------------
// 512 threads (8 waves), BM=128 rows/block, full N=128, K=256 in 2 phases of 128.
// LDS: A 128x128 bf16 (32KB) + B 128x128 bf16 (32KB), XOR-swizzled rows.

__global__ __launch_bounds__(512) void k_gemm(const unsigned short* __restrict__ aggB,
                                              const unsigned short* __restrict__ xinB,
                                              const unsigned short* __restrict__ VT,
                                              const float* __restrict__ bias,
                                              float* __restrict__ outF,
                                              unsigned short* __restrict__ outB,
                                              int mode /*1 = relu+bf16 out, 0 = fp32 out*/,
                                              int nrows) {
    __shared__ char As[32768];
    __shared__ char Bs[32768];
    int tid = threadIdx.x;
    int w = tid >> 6, l = tid & 63;
    int r0 = blockIdx.x * 128;

    f32x4 acc[8] = {};

    int arow = w * 16 + (l & 15);
    int kgrp = (l >> 4) * 8;

    for (int p = 0; p < 2; ++p) {
        const unsigned short* Asrc = p ? xinB : aggB;
        // stage A: 128 rows x 128 k = 2048 x 16B chunks
#pragma unroll
        for (int q = 0; q < 4; ++q) {
            int c = tid + q * 512;
            int m = c >> 4, c16 = c & 15;
            int gr = r0 + m;
            uint4 v = make_uint4(0, 0, 0, 0);
            if (gr < nrows) v = *(const uint4*)(Asrc + (size_t)gr * HID + c16 * 8);
            int byt = (m * 256 + c16 * 16) ^ ((m & 7) << 4);
            *(uint4*)(As + byt) = v;
        }
        // stage B: V_T rows j, k-half p
#pragma unroll
        for (int q = 0; q < 4; ++q) {
            int c = tid + q * 512;
            int j = c >> 4, c16 = c & 15;
            uint4 v = *(const uint4*)(VT + (size_t)j * 256 + p * 128 + c16 * 8);
            int byt = (j * 256 + c16 * 16) ^ ((j & 7) << 4);
            *(uint4*)(Bs + byt) = v;
        }
        __syncthreads();

#pragma unroll
        for (int s = 0; s < 4; ++s) {
            int koff = (s * 32 + kgrp) * 2;
            bf16x8 a = *(const bf16x8*)(As + ((arow * 256 + koff) ^ ((arow & 7) << 4)));
#pragma unroll
            for (int cc = 0; cc < 8; ++cc) {
                int brow = cc * 16 + (l & 15);
                bf16x8 b = *(const bf16x8*)(Bs + ((brow * 256 + koff) ^ ((brow & 7) << 4)));
                acc[cc] = __builtin_amdgcn_mfma_f32_16x16x32_bf16(a, b, acc[cc], 0, 0, 0);
            }
        }
        __syncthreads();
    }

    // epilogue: D[row=(l>>4)*4+i][col=cc*16+(l&15)] per wave tile
    int lo = l & 15, hi = l >> 4;
#pragma unroll
    for (int cc = 0; cc < 8; ++cc) {
        int col = cc * 16 + lo;
        float bv = bias[col];
#pragma unroll
        for (int i = 0; i < 4; ++i) {
            int gr = r0 + w * 16 + hi * 4 + i;
            if (gr < nrows) {
                float v = acc[cc][i] + bv;
                if (mode) {
                    v = fmaxf(v, 0.f);
                    outB[(size_t)gr * HID + col] = f2b(v);
                } else {
                    outF[(size_t)gr * HID + col] = v;
                }
            }
        }
    }
}

// ---------------- launch ----------------

extern "C" void kernel_launch(void* const* d_in, const int* in_sizes, int n_in,
                              void* d_out, int out_size, void* d_ws, size_t ws_size,
                              hipStream_t stream) {
    const float* x   = (const float*)d_in[0];
    const int*   ei  = (const int*)d_in[1];
    const float* W1l = (const float*)d_in[2];
    const float* b1l = (const float*)d_in[3];
    const float* W1r = (const float*)d_in[4];
    const float* W2l = (const float*)d_in[5];
    const float* b2l = (const float*)d_in[6];
    const float* W2r = (const float*)d_in[7];
    float* out = (float*)d_out;

    const int* src = ei;
    const int* dst = ei + N_EDGES;

    char* w = (char*)d_ws;
    unsigned short* aggB = (unsigned short*)(w);                    // 12,800,000 B
    unsigned short* buf0 = (unsigned short*)(w + 12800000);         // 12,800,000 B (xb, then hb in place)
    int*   csr     = (int*)(w + 25600000);                          //  2,400,000 B
    int*   row_off = (int*)(w + 28000000);                          //    200,192 B
    int*   fill    = (int*)(w + 28200192);                          //    200,192 B
    float* inv_deg = (float*)(w + 28400384);                        //    200,192 B
    unsigned short* V1 = (unsigned short*)(w + 28600576);           //     65,536 B
    unsigned short* V2 = (unsigned short*)(w + 28666112);           //     65,536 B
    int*   bsum    = (int*)(w + 28731648);                          //      1,024 B

    // CSR build
    hipMemsetAsync(fill, 0, N_NODES * sizeof(int), stream);
    k_deg<<<(N_EDGES + 255) / 256, 256, 0, stream>>>(dst, fill, N_EDGES);
    k_bsum<<<SCAN_BLOCKS, 256, 0, stream>>>(fill, bsum, N_NODES);
    k_scan_bsum<<<1, 256, 0, stream>>>(bsum, row_off, SCAN_BLOCKS, N_NODES);
    k_write_off<<<SCAN_BLOCKS, 256, 0, stream>>>(fill, bsum, row_off, inv_deg, N_NODES);
    k_place<<<(N_EDGES + 255) / 256, 256, 0, stream>>>(src, dst, row_off, fill, csr, N_EDGES);

    // weights + x cast
    k_prepV<<<(2 * 128 * 256 + 255) / 256, 256, 0, stream>>>(W1l, W1r, W2l, W2r, V1, V2);
    k_cast<<<(N_NODES * HID / 4 + 255) / 256, 256, 0, stream>>>(x, buf0, N_NODES * HID / 4);

    const int gemm_grid = (N_NODES + 127) / 128;  // 391

    // layer 1: agg1 <- mean(xb); h(bf16, relu) -> buf0 in place
    k_agg<<<(N_NODES * 32 + 255) / 256, 256, 0, stream>>>(buf0, csr, row_off, inv_deg, aggB, N_NODES);
    k_gemm<<<gemm_grid, 512, 0, stream>>>(aggB, buf0, V1, b1l, out, buf0, 1, N_NODES);

    // layer 2: agg2 <- mean(hb); out(fp32) -> d_out
    k_agg<<<(N_NODES * 32 + 255) / 256, 256, 0, stream>>>(buf0, csr, row_off, inv_deg, aggB, N_NODES);
    k_gemm<<<gemm_grid, 512, 0, stream>>>(aggB, buf0, V2, b2l, out, buf0, 0, N_NODES);
}